// Round 10
// baseline (328.783 us; speedup 1.0000x reference)
//
#include <hip/hip_runtime.h>

// LSTM B=4096, T=512, I=1, H=64, O=1 (fp32 in/out).
// Round 10 = r9 (294us steady) + transcendental-count reduction:
//  (1) exp2 pre-scaling: W_hh/w_ih/bias rows pre-multiplied by -log2e (i,f,o)
//      or +2log2e (g) -> MFMA outputs ARE the exp2 arguments. Deletes the
//      per-gate arg muls and sign handling.
//  (2) shared reciprocals: sigmoid/tanh are all 1/(1+E). Group {Di,Df,Dg}
//      -> ONE v_rcp of the product (recover each via 7 muls); {Do,Dc} -> one
//      more. 10 trans/cell -> 7 (5 exp2 + 2 rcp). Overflow-safe unclamped
//      (|gate|<=8.9 -> product exponent <=78 < 128); only the c-arg needs
//      fmin(.,64) since |c| can reach ~512.
//  (3) C-operand (x*w_ih+bias) software-pipelined: refreshed for t+1 in the
//      MFMA shadow of step t (h-independent, sh_x is static).
//  (4) phase-stagger retuned to ~640 cyc (half the predicted new step).
// Structure (r4/r9): MB=8, grid=512 (2 blocks/CU). hi/lo of h packed into M:
// row 2q=hi, 2q+1=lo of batch q; 8 MFMA/wave-step; all 4 gates of a cell in
// one lane's acc regs (2 cells/lane); one barrier/step; ping-pong h buffers.
// MFMA layouts (m89-verified): A[m=lane&15][k=(lane>>4)*8+i],
// B[k=(lane>>4)*8+i][n=lane&15], D[m=(lane>>4)*4+r][n=lane&15].

#define TT   512
#define MB   8
#define HP   72            // f16 row stride (144 B): 16B-aligned, 2-way max
#define BUFE (16 * HP)     // one ping-pong buffer: 16 rows
#define SXP  10            // sh_x row stride (floats)

#define L2E  1.4426950408889634f
#define L2E2 2.8853900817779268f

typedef _Float16 f16x8 __attribute__((ext_vector_type(8)));
typedef float    f32x4 __attribute__((ext_vector_type(4)));

#define MFMA16(a, b, c) __builtin_amdgcn_mfma_f32_16x16x32_f16((a), (b), (c), 0, 0, 0)

__device__ __forceinline__ float rcp_(float x)  { return __builtin_amdgcn_rcpf(x); }
__device__ __forceinline__ float exp2_(float x) { return __builtin_amdgcn_exp2f(x); }

__device__ __forceinline__ f16x8 cvt8s(const float4& u0, const float4& u1, float s) {
    f16x8 r;
    r[0] = (_Float16)(u0.x * s); r[1] = (_Float16)(u0.y * s);
    r[2] = (_Float16)(u0.z * s); r[3] = (_Float16)(u0.w * s);
    r[4] = (_Float16)(u1.x * s); r[5] = (_Float16)(u1.y * s);
    r[6] = (_Float16)(u1.z * s); r[7] = (_Float16)(u1.w * s);
    return r;
}

__global__ __launch_bounds__(256, 2) void lstm_mfma(
    const float* __restrict__ x,      // [4096, 512]
    const float* __restrict__ w_ih,   // [256]
    const float* __restrict__ w_hh,   // [256, 64]
    const float* __restrict__ b_ih,   // [256]
    const float* __restrict__ b_hh,   // [256]
    const float* __restrict__ w_out,  // [64]
    const float* __restrict__ b_out,  // [1]
    float* __restrict__ out)          // [4096]
{
    __shared__ __align__(16) float    sh_x[TT * SXP];   // [t][m], 20 KB
    __shared__ __align__(16) _Float16 hbuf[2 * BUFE];   // 4.6 KB

    const int tid = threadIdx.x;
    const int w   = tid >> 6;    // wave 0..3 (owns N-tiles {w, w+4, w+8, w+12})
    const int L   = tid & 63;
    const int l16 = L & 15;
    const int h0  = L >> 4;      // 0..3
    const int b0  = blockIdx.x * MB;
    const int j   = 16 * w + l16;  // hidden unit col owned by this lane

    // ---- stage x: sh_x[t*SXP + m] = x[b0+m][t] (coalesced) ----
    {
        const int q = tid >> 5;   // batch 0..7
        const int l = tid & 31;
        const float* xr = x + (size_t)(b0 + q) * TT;
        #pragma unroll
        for (int i = 0; i < TT / 32; ++i)
            sh_x[(l + 32 * i) * SXP + q] = xr[l + 32 * i];
    }
    // ---- zero both h buffers ----
    for (int i = tid; i < 2 * BUFE; i += 256) hbuf[i] = (_Float16)0.0f;

    // ---- preload W_hh fragments, pre-scaled so MFMA outputs are exp2 args:
    // gates i,f,o: sigmoid(v)=1/(1+2^(-v*L2E)) -> scale -L2E
    // gate  g:     tanh(v)=1-2/(1+2^(v*2L2E)) -> scale +2*L2E
    const float sc[4] = {-L2E, -L2E, L2E2, -L2E};
    f16x8 Bf[4][2];
    float wihv[4], biasv[4];
    #pragma unroll
    for (int s = 0; s < 4; ++s) {
        const int n = 64 * s + j;
        #pragma unroll
        for (int kt = 0; kt < 2; ++kt) {
            const float* p = w_hh + n * 64 + kt * 32 + h0 * 8;
            float4 u0 = *(const float4*)p;
            float4 u1 = *(const float4*)(p + 4);
            Bf[s][kt] = cvt8s(u0, u1, sc[s]);
        }
        wihv[s]  = w_ih[n] * sc[s];
        biasv[s] = (b_ih[n] + b_hh[n]) * sc[s];
    }

    // lane's A row m=l16: batch l16>>1, plane l16&1 (even=hi, odd=lo)
    const int aoff = l16 * HP + h0 * 8;   // f16 units; +32 for K-chunk 1
    // lane's cells: batches q0=2h0, q0+1; writes rows 4h0..4h0+3, col j
    const int xoff = 2 * h0;
    const int wr   = 4 * h0 * HP + j;

    float cc0 = 0.0f, cc1 = 0.0f;

    // shared-rcp cell update: args are exp2-ready; returns h, updates cc
    auto cellup = [&](float ai, float af, float ag, float ao, float& cc) -> float {
        float Ei = exp2_(ai), Ef = exp2_(af), Eg = exp2_(ag);
        float Di = 1.0f + Ei, Df = 1.0f + Ef, Dg = 1.0f + Eg;
        float Pif = Di * Df;
        float u   = rcp_(Pif * Dg);
        float si  = u * (Df * Dg);                 // sigmoid(i)
        float sf  = u * (Di * Dg);                 // sigmoid(f)
        float tg  = fmaf(-2.0f, u * Pif, 1.0f);    // tanh(g)
        cc = fmaf(sf, cc, si * tg);
        float Ec = exp2_(fminf(cc * L2E2, 64.0f));
        float Eo = exp2_(ao);
        float Dc = 1.0f + Ec, Do = 1.0f + Eo;
        float u2 = rcp_(Do * Dc);
        return (u2 * Dc) * fmaf(-2.0f, u2 * Do, 1.0f);  // sigmoid(o)*tanh(c)
    };

    // C-operand pipeline: ci[s] rows 0,2 = x*w_ih+bias for batches 2h0,2h0+1
    f32x4 ci[4];
    {
        const float2 x0 = *(const float2*)(sh_x + 0 * SXP + xoff);
        #pragma unroll
        for (int s = 0; s < 4; ++s) {
            ci[s][0] = fmaf(x0.x, wihv[s], biasv[s]);
            ci[s][1] = 0.0f;
            ci[s][2] = fmaf(x0.y, wihv[s], biasv[s]);
            ci[s][3] = 0.0f;
        }
    }

    __syncthreads();

    // ---- phase stagger: desync co-resident blocks by ~half a step ----
    if (((blockIdx.x >> 8) ^ blockIdx.x) & 1) {
        __builtin_amdgcn_s_sleep(10);   // ~640 cyc
    }

    auto step = [&](const _Float16* rb, _Float16* wb, int t) {
        // A fragments: one row, 2 K-chunks
        f16x8 a0 = *(const f16x8*)(rb + aoff);
        f16x8 a1 = *(const f16x8*)(rb + aoff + 32);

        f32x4 acc[4];
        #pragma unroll
        for (int s = 0; s < 4; ++s)
            acc[s] = MFMA16(a1, Bf[s][1], MFMA16(a0, Bf[s][0], ci[s]));

        // refresh ci for t+1 in the MFMA shadow (h-independent)
        if (t + 1 < TT) {
            const float2 xn = *(const float2*)(sh_x + (t + 1) * SXP + xoff);
            #pragma unroll
            for (int s = 0; s < 4; ++s) {
                ci[s][0] = fmaf(xn.x, wihv[s], biasv[s]);
                ci[s][2] = fmaf(xn.y, wihv[s], biasv[s]);
            }
        }

        // cell 0: batch 2h0 (arg = acc[.][0] + acc[.][1], hi+lo rows)
        {
            float hv = cellup(acc[0][0] + acc[0][1], acc[1][0] + acc[1][1],
                              acc[2][0] + acc[2][1], acc[3][0] + acc[3][1], cc0);
            _Float16 hh = (_Float16)hv;
            wb[wr]      = hh;                          // row 4h0   (hi)
            wb[wr + HP] = (_Float16)(hv - (float)hh);  // row 4h0+1 (lo)
        }
        // cell 1: batch 2h0+1 (arg = acc[.][2] + acc[.][3])
        {
            float hv = cellup(acc[0][2] + acc[0][3], acc[1][2] + acc[1][3],
                              acc[2][2] + acc[2][3], acc[3][2] + acc[3][3], cc1);
            _Float16 hh = (_Float16)hv;
            wb[wr + 2 * HP] = hh;                          // row 4h0+2 (hi)
            wb[wr + 3 * HP] = (_Float16)(hv - (float)hh);  // row 4h0+3 (lo)
        }
        __syncthreads();
    };

    for (int t = 0; t < TT; t += 2) {
        step(hbuf,        hbuf + BUFE, t);      // read buf0, write buf1
        step(hbuf + BUFE, hbuf,        t + 1);  // read buf1, write buf0
    }

    // ---- epilogue: final h in buf0; wave w reduces batches 2w, 2w+1 ----
    const float wo = w_out[L];
    #pragma unroll
    for (int p = 0; p < 2; ++p) {
        const int q = 2 * w + p;
        float hvf = (float)hbuf[(2 * q) * HP + L] + (float)hbuf[(2 * q + 1) * HP + L];
        float v = hvf * wo;
        #pragma unroll
        for (int off = 32; off; off >>= 1) v += __shfl_down(v, off);
        if (L == 0) out[b0 + q] = v + b_out[0];
    }
}

extern "C" void kernel_launch(void* const* d_in, const int* in_sizes, int n_in,
                              void* d_out, int out_size, void* d_ws, size_t ws_size,
                              hipStream_t stream) {
    const float* x     = (const float*)d_in[0];
    const float* w_ih  = (const float*)d_in[1];
    const float* w_hh  = (const float*)d_in[2];
    const float* b_ih  = (const float*)d_in[3];
    const float* b_hh  = (const float*)d_in[4];
    const float* w_out = (const float*)d_in[5];
    const float* b_out = (const float*)d_in[6];
    float* out = (float*)d_out;

    lstm_mfma<<<4096 / MB, 256, 0, stream>>>(x, w_ih, w_hh, b_ih, b_hh,
                                             w_out, b_out, out);
}